// Round 4
// baseline (948.251 us; speedup 1.0000x reference)
//
#include <hip/hip_runtime.h>

#define HIDDEN 32
#define FOUR_H 128
#define FUT 6
#define BSZ 256
#define TT 2048
#define FF 64
#define CH 8                       // timesteps per LDS chunk
#define CHB (CH * FOUR_H * 4)      // 4096 bytes per chunk
#define WAVES 8                    // waves (chains) per workgroup -> 2 per SIMD

typedef float f32x2 __attribute__((ext_vector_type(2)));

__device__ __forceinline__ float fast_rcp(float x)  { return __builtin_amdgcn_rcpf(x); }
__device__ __forceinline__ float fast_exp2(float x) { return __builtin_amdgcn_exp2f(x); }
__device__ __forceinline__ float sigmoid_f(float x) {
    float t = fast_exp2(x * -1.44269504088896340736f);
    return fast_rcp(1.0f + t);
}

__device__ __forceinline__ void gload_lds16(const void* g, void* l) {
    __builtin_amdgcn_global_load_lds(
        (const __attribute__((address_space(1))) void*)g,
        (__attribute__((address_space(3))) void*)l, 16, 0, 0);
}

// ---------------------------------------------------------------------------
// Kernel 1: x_proj = X @ Wx + b for timesteps [t0, t0+cur), cur % 64 == 0.
// Output layout (per batch b): chunks of CH=8 timesteps, each chunk stored as
// [u4][j][um] with t_in_chunk = u4*4+um  (2 sub-blocks of [128][4] floats).
// ---------------------------------------------------------------------------
__global__ __launch_bounds__(256) void xproj_kernel(
    const float* __restrict__ X, const float* __restrict__ Wx,
    const float* __restrict__ bias, float* __restrict__ xg,
    int t0, int cur)
{
    __shared__ float sW[64][128];
    __shared__ float sX[64][65];

    int tid = threadIdx.x;
    long rowBase = (long)blockIdx.x * 64;   // 64 consecutive t within one b

    const float4* W4 = (const float4*)Wx;
    float4* sW4 = (float4*)&sW[0][0];
#pragma unroll
    for (int i = 0; i < 8; ++i) sW4[tid + 256 * i] = W4[tid + 256 * i];

#pragma unroll
    for (int i = 0; i < 4; ++i) {
        int idx = tid + 256 * i;
        int row = idx >> 4;
        int kq  = idx & 15;
        int r   = (int)rowBase + row;
        int bb  = r / cur;
        int tc  = r - bb * cur;
        const float4* xp = (const float4*)(X + ((long)bb * TT + t0 + tc) * FF);
        float4 v = xp[kq];
        sX[kq * 4 + 0][row] = v.x;
        sX[kq * 4 + 1][row] = v.y;
        sX[kq * 4 + 2][row] = v.z;
        sX[kq * 4 + 3][row] = v.w;
    }
    __syncthreads();

    int cq = tid & 31;
    int rg = tid >> 5;

    float4 bv = *(const float4*)(bias + cq * 4);
    float4 acc[8];
#pragma unroll
    for (int i = 0; i < 8; ++i) acc[i] = bv;

#pragma unroll 8
    for (int k = 0; k < 64; ++k) {
        float4 w = *(const float4*)&sW[k][cq * 4];
#pragma unroll
        for (int i = 0; i < 8; ++i) {
            float x = sX[k][rg * 8 + i];
            acc[i].x = fmaf(x, w.x, acc[i].x);
            acc[i].y = fmaf(x, w.y, acc[i].y);
            acc[i].z = fmaf(x, w.z, acc[i].z);
            acc[i].w = fmaf(x, w.w, acc[i].w);
        }
    }
    __syncthreads();   // reuse sW as output staging [t][j]

#pragma unroll
    for (int i = 0; i < 8; ++i)
        *(float4*)&sW[rg * 8 + i][cq * 4] = acc[i];
    __syncthreads();

    // emit permuted layout with linear coalesced stores
#pragma unroll
    for (int i = 0; i < 8; ++i) {
        int f  = tid + i * 256;          // float4 index within the 32KB tile
        int j  = f & 127;
        int u4 = (f >> 7) & 1;
        int nl = f >> 8;                 // 8-step chunk within the 64-t tile
        int tl = nl * 8 + u4 * 4;
        float4 v;
        v.x = sW[tl + 0][j];
        v.y = sW[tl + 1][j];
        v.z = sW[tl + 2][j];
        v.w = sW[tl + 3][j];
        *(float4*)(xg + rowBase * FOUR_H + (long)f * 4) = v;
    }
}

// ---------------------------------------------------------------------------
// Kernel 2: sequential LSTM scan. 8 waves per block, one chain per wave
// (2 waves per SIMD -> 2-cycle issue cadence, mutual stall hiding).
// GEMV via v_pk_fma_f32 over k-pairs; h broadcast as SGPR pairs (readlane).
// ---------------------------------------------------------------------------
__global__ __launch_bounds__(512) void lstm_rec_kernel(
    const float* __restrict__ xg, const float* __restrict__ Wh,
    const float* __restrict__ Wd, const float* __restrict__ bd,
    float* __restrict__ state, float* __restrict__ out,
    int cur, int first, int last)
{
    __shared__ float sxg[WAVES * 2 * CH * FOUR_H];   // 64 KB: 8 KB dbuf per wave

    int wave = threadIdx.x >> 6;
    int l = threadIdx.x & 63;
    int b = blockIdx.x * WAVES + wave;
    int kl = l & 31;
    bool lowHalf = (l < 32);

    float* myLds = sxg + wave * (2 * CH * FOUR_H);

    // recurrent weights as k-interleaved pairs: wh0p[m] = (Wh[2m][l], Wh[2m+1][l])
    f32x2 wh0p[16], wh1p[16];
#pragma unroll
    for (int m = 0; m < 16; ++m) {
        wh0p[m][0] = Wh[(2 * m) * FOUR_H + l];
        wh0p[m][1] = Wh[(2 * m + 1) * FOUR_H + l];
        wh1p[m][0] = Wh[(2 * m) * FOUR_H + 64 + l];
        wh1p[m][1] = Wh[(2 * m + 1) * FOUR_H + 64 + l];
    }

    float c, h;
    if (first) { c = 0.0f; h = 0.0f; }
    else       { c = state[b * 64 + kl]; h = state[b * 64 + 32 + kl]; }

    const char* xpc = (const char*)(xg + (size_t)b * cur * FOUR_H);

    const float L2E = 1.44269504088896340736f;
    float s1 = lowHalf ? (-2.0f * L2E) : (-L2E);
    float m1 = lowHalf ? 2.0f : 1.0f;
    float a1 = lowHalf ? -1.0f : 0.0f;

#define ISSUE_CHUNK(nn)                                                      \
    {                                                                        \
        const char* src = xpc + (size_t)(nn) * CHB + l * 16;                 \
        char* dstb = (char*)myLds + ((nn) & 1) * CHB;                        \
        _Pragma("unroll")                                                    \
        for (int i = 0; i < 4; ++i)                                          \
            gload_lds16(src + i * 1024, dstb + i * 1024);                    \
    }

#define STEP_BODY(Z0, Z1)                                                    \
    {                                                                        \
        f32x2 hp[16];                                                        \
        _Pragma("unroll")                                                    \
        for (int m = 0; m < 16; ++m) {                                       \
            hp[m][0] = __int_as_float(__builtin_amdgcn_readlane(__float_as_int(h), 2 * m));     \
            hp[m][1] = __int_as_float(__builtin_amdgcn_readlane(__float_as_int(h), 2 * m + 1)); \
        }                                                                    \
        f32x2 a0a = hp[0] * wh0p[0], a0b = hp[1] * wh0p[1];                  \
        f32x2 a1a = hp[0] * wh1p[0], a1b = hp[1] * wh1p[1];                  \
        _Pragma("unroll")                                                    \
        for (int m = 2; m < 16; m += 2) {                                    \
            a0a = __builtin_elementwise_fma(hp[m],     wh0p[m],     a0a);    \
            a0b = __builtin_elementwise_fma(hp[m + 1], wh0p[m + 1], a0b);    \
            a1a = __builtin_elementwise_fma(hp[m],     wh1p[m],     a1a);    \
            a1b = __builtin_elementwise_fma(hp[m + 1], wh1p[m + 1], a1b);    \
        }                                                                    \
        f32x2 s0p = a0a + a0b;                                               \
        f32x2 s1p = a1a + a1b;                                               \
        float A0 = (Z0) + s0p[0] + s0p[1];                                   \
        float A1 = (Z1) + s1p[0] + s1p[1];                                   \
        float act0 = sigmoid_f(A0);                                          \
        float u1 = fast_rcp(1.0f + fast_exp2(A1 * s1));                      \
        float act1 = fmaf(u1, m1, a1);                                       \
        float gi = act0, gf = act0;                                          \
        asm("v_permlane32_swap_b32 %0, %1" : "+v"(gi), "+v"(gf));            \
        float gg = act1, go = act1;                                          \
        asm("v_permlane32_swap_b32 %0, %1" : "+v"(gg), "+v"(go));            \
        c = fmaf(gf, c, gi * gg);                                            \
        float uc = fast_rcp(1.0f + fast_exp2(c * -2.88539008177792681472f)); \
        float tc2 = fmaf(uc, 2.0f, -1.0f);                                   \
        h = go * tc2;                                                        \
    }

    int nFull = cur / CH;   // cur is a multiple of 64, no tail

    ISSUE_CHUNK(0)
    for (int n = 0; n < nFull; ++n) {
        if (n + 1 < nFull) {
            ISSUE_CHUNK(n + 1)
            asm volatile("s_waitcnt vmcnt(4)" ::: "memory");
        } else {
            asm volatile("s_waitcnt vmcnt(0)" ::: "memory");
        }
        const float4* sb = (const float4*)((char*)myLds + (n & 1) * CHB);
        float4 z0q[2], z1q[2];
#pragma unroll
        for (int u4 = 0; u4 < 2; ++u4) {
            z0q[u4] = sb[u4 * 128 + l];
            z1q[u4] = sb[u4 * 128 + 64 + l];
        }
#pragma unroll
        for (int u4 = 0; u4 < 2; ++u4) {
            STEP_BODY(z0q[u4].x, z1q[u4].x)
            STEP_BODY(z0q[u4].y, z1q[u4].y)
            STEP_BODY(z0q[u4].z, z1q[u4].z)
            STEP_BODY(z0q[u4].w, z1q[u4].w)
        }
    }

#undef STEP_BODY
#undef ISSUE_CHUNK

    if (last) {
        float e = (h > 0.0f) ? h : (fast_exp2(h * L2E) - 1.0f);
#pragma unroll
        for (int q = 0; q < FUT; ++q) {
            float v = lowHalf ? e * Wd[kl * FUT + q] : 0.0f;
#pragma unroll
            for (int off = 1; off < 64; off <<= 1)
                v += __shfl_xor(v, off);
            if (l == 0) out[b * FUT + q] = v + bd[q];
        }
    } else {
        if (lowHalf) {
            state[b * 64 + kl]      = c;
            state[b * 64 + 32 + kl] = h;
        }
    }
}

// ---------------------------------------------------------------------------
extern "C" void kernel_launch(void* const* d_in, const int* in_sizes, int n_in,
                              void* d_out, int out_size, void* d_ws, size_t ws_size,
                              hipStream_t stream)
{
    const float* X    = (const float*)d_in[0];
    const float* Wx   = (const float*)d_in[1];
    const float* Wh   = (const float*)d_in[2];
    const float* bias = (const float*)d_in[3];
    const float* Wd   = (const float*)d_in[4];
    const float* bd   = (const float*)d_in[5];
    float* out = (float*)d_out;

    float* state = (float*)d_ws;
    size_t stateBytes = (size_t)BSZ * 64 * sizeof(float);
    float* xgbuf = (float*)((char*)d_ws + stateBytes);

    size_t avail = ws_size > stateBytes ? ws_size - stateBytes : 0;
    size_t perT = (size_t)BSZ * FOUR_H * sizeof(float);
    long TcL = (long)(avail / perT);
    TcL &= ~63L;                       // multiple of 64 (layout requirement)
    int Tc = (TcL > TT) ? TT : (int)TcL;
    if (Tc < 64) return;

    for (int t0 = 0; t0 < TT; t0 += Tc) {
        int cur = (TT - t0 < Tc) ? (TT - t0) : Tc;
        int blocks = (BSZ * cur) / 64;
        xproj_kernel<<<dim3(blocks), dim3(256), 0, stream>>>(X, Wx, bias, xgbuf, t0, cur);
        lstm_rec_kernel<<<dim3(BSZ / WAVES), dim3(WAVES * 64), 0, stream>>>(
            xgbuf, Wh, Wd, bd, state, out, cur, (t0 == 0) ? 1 : 0,
            (t0 + cur >= TT) ? 1 : 0);
    }
}

// Round 5
// 536.562 us; speedup vs baseline: 1.7673x; 1.7673x over previous
//
#include <hip/hip_runtime.h>

#define HIDDEN 32
#define FOUR_H 128
#define FUT 6
#define BSZ 256
#define TT 2048
#define FF 64
#define CH 16                      // timesteps per LDS chunk
#define CHB (CH * FOUR_H * 4)      // 8192 bytes per chunk

typedef float f32x2 __attribute__((ext_vector_type(2)));

__device__ __forceinline__ float fast_rcp(float x)  { return __builtin_amdgcn_rcpf(x); }
__device__ __forceinline__ float fast_exp2(float x) { return __builtin_amdgcn_exp2f(x); }
__device__ __forceinline__ float sigmoid_f(float x) {
    float t = fast_exp2(x * -1.44269504088896340736f);
    return fast_rcp(1.0f + t);
}

__device__ __forceinline__ void gload_lds16(const void* g, void* l) {
    __builtin_amdgcn_global_load_lds(
        (const __attribute__((address_space(1))) void*)g,
        (__attribute__((address_space(3))) void*)l, 16, 0, 0);
}

// ---------------------------------------------------------------------------
// Kernel 1: x_proj = X @ Wx + b for timesteps [t0, t0+cur), cur % 64 == 0.
// Output layout (per batch b): chunks of 16 timesteps, each chunk stored as
// [u4][j][um] with t_in_chunk = u4*4+um  (4 sub-blocks of [128][4] floats).
// ---------------------------------------------------------------------------
__global__ __launch_bounds__(256) void xproj_kernel(
    const float* __restrict__ X, const float* __restrict__ Wx,
    const float* __restrict__ bias, float* __restrict__ xg,
    int t0, int cur)
{
    __shared__ float sW[64][128];
    __shared__ float sX[64][65];

    int tid = threadIdx.x;
    long rowBase = (long)blockIdx.x * 64;   // 64 consecutive t within one b

    const float4* W4 = (const float4*)Wx;
    float4* sW4 = (float4*)&sW[0][0];
#pragma unroll
    for (int i = 0; i < 8; ++i) sW4[tid + 256 * i] = W4[tid + 256 * i];

#pragma unroll
    for (int i = 0; i < 4; ++i) {
        int idx = tid + 256 * i;
        int row = idx >> 4;
        int kq  = idx & 15;
        int r   = (int)rowBase + row;
        int bb  = r / cur;
        int tc  = r - bb * cur;
        const float4* xp = (const float4*)(X + ((long)bb * TT + t0 + tc) * FF);
        float4 v = xp[kq];
        sX[kq * 4 + 0][row] = v.x;
        sX[kq * 4 + 1][row] = v.y;
        sX[kq * 4 + 2][row] = v.z;
        sX[kq * 4 + 3][row] = v.w;
    }
    __syncthreads();

    int cq = tid & 31;
    int rg = tid >> 5;

    float4 bv = *(const float4*)(bias + cq * 4);
    float4 acc[8];
#pragma unroll
    for (int i = 0; i < 8; ++i) acc[i] = bv;

#pragma unroll 8
    for (int k = 0; k < 64; ++k) {
        float4 w = *(const float4*)&sW[k][cq * 4];
#pragma unroll
        for (int i = 0; i < 8; ++i) {
            float x = sX[k][rg * 8 + i];
            acc[i].x = fmaf(x, w.x, acc[i].x);
            acc[i].y = fmaf(x, w.y, acc[i].y);
            acc[i].z = fmaf(x, w.z, acc[i].z);
            acc[i].w = fmaf(x, w.w, acc[i].w);
        }
    }
    __syncthreads();   // reuse sW as output staging [t][j]

#pragma unroll
    for (int i = 0; i < 8; ++i)
        *(float4*)&sW[rg * 8 + i][cq * 4] = acc[i];
    __syncthreads();

    // emit permuted layout with linear coalesced stores
#pragma unroll
    for (int i = 0; i < 8; ++i) {
        int f  = tid + i * 256;          // float4 index within the 32KB tile
        int j  = f & 127;
        int u4 = (f >> 7) & 3;
        int nl = f >> 9;
        int tl = nl * 16 + u4 * 4;
        float4 v;
        v.x = sW[tl + 0][j];
        v.y = sW[tl + 1][j];
        v.z = sW[tl + 2][j];
        v.w = sW[tl + 3][j];
        *(float4*)(xg + rowBase * FOUR_H + (long)f * 4) = v;
    }
}

// ---------------------------------------------------------------------------
// Kernel 2: sequential LSTM scan. One wave per batch element (1 chain/CU).
// h-broadcast via LDS: 1 ds_write_b32 + 8 uniform-address ds_read_b128
// (no readlane/SGPR traffic); GEMV = 32 v_pk_fma_f32.
// ---------------------------------------------------------------------------
__global__ __launch_bounds__(64) void lstm_rec_kernel(
    const float* __restrict__ xg, const float* __restrict__ Wh,
    const float* __restrict__ Wd, const float* __restrict__ bd,
    float* __restrict__ state, float* __restrict__ out,
    int cur, int first, int last)
{
    __shared__ float sxg[2 * CH * FOUR_H];   // 16 KB double buffer
    __shared__ float sh[32];                 // h broadcast slab

    int b = blockIdx.x;
    int l = threadIdx.x;
    int kl = l & 31;
    bool lowHalf = (l < 32);

    // recurrent weights as k-interleaved pairs: wh0p[m] = (Wh[2m][l], Wh[2m+1][l])
    f32x2 wh0p[16], wh1p[16];
#pragma unroll
    for (int m = 0; m < 16; ++m) {
        wh0p[m][0] = Wh[(2 * m) * FOUR_H + l];
        wh0p[m][1] = Wh[(2 * m + 1) * FOUR_H + l];
        wh1p[m][0] = Wh[(2 * m) * FOUR_H + 64 + l];
        wh1p[m][1] = Wh[(2 * m + 1) * FOUR_H + 64 + l];
    }

    float c, h;
    if (first) { c = 0.0f; h = 0.0f; }
    else       { c = state[b * 64 + kl]; h = state[b * 64 + 32 + kl]; }

    const char* xpc = (const char*)(xg + (size_t)b * cur * FOUR_H);
    const float4* shq = (const float4*)sh;

    const float L2E = 1.44269504088896340736f;
    float s1 = lowHalf ? (-2.0f * L2E) : (-L2E);
    float m1 = lowHalf ? 2.0f : 1.0f;
    float a1 = lowHalf ? -1.0f : 0.0f;

#define ISSUE_CHUNK(nn)                                                      \
    {                                                                        \
        const char* src = xpc + (size_t)(nn) * CHB + l * 16;                 \
        char* dstb = (char*)sxg + ((nn) & 1) * CHB;                         \
        _Pragma("unroll")                                                    \
        for (int i = 0; i < 8; ++i)                                          \
            gload_lds16(src + i * 1024, dstb + i * 1024);                    \
    }

#define STEP_BODY(Z0, Z1)                                                    \
    {                                                                        \
        sh[kl] = h;                       /* 1 ds_write, 2-way same-addr */  \
        float4 hq[8];                                                        \
        _Pragma("unroll")                                                    \
        for (int q = 0; q < 8; ++q) hq[q] = shq[q];  /* uniform broadcast */ \
        f32x2 a0 = {(Z0), 0.0f}, b0 = {0.0f, 0.0f};                          \
        f32x2 a1v = {(Z1), 0.0f}, b1 = {0.0f, 0.0f};                         \
        _Pragma("unroll")                                                    \
        for (int q = 0; q < 8; ++q) {                                        \
            f32x2 hlo = {hq[q].x, hq[q].y};                                  \
            f32x2 hhi = {hq[q].z, hq[q].w};                                  \
            a0  = __builtin_elementwise_fma(hlo, wh0p[2 * q],     a0);       \
            b0  = __builtin_elementwise_fma(hhi, wh0p[2 * q + 1], b0);       \
            a1v = __builtin_elementwise_fma(hlo, wh1p[2 * q],     a1v);      \
            b1  = __builtin_elementwise_fma(hhi, wh1p[2 * q + 1], b1);       \
        }                                                                    \
        f32x2 s0p = a0 + b0;                                                 \
        f32x2 s1p = a1v + b1;                                                \
        float A0 = s0p[0] + s0p[1];                                          \
        float A1 = s1p[0] + s1p[1];                                          \
        float act0 = sigmoid_f(A0);                                          \
        float u1 = fast_rcp(1.0f + fast_exp2(A1 * s1));                      \
        float act1 = fmaf(u1, m1, a1);                                       \
        float gi = act0, gf = act0;                                          \
        asm("v_permlane32_swap_b32 %0, %1" : "+v"(gi), "+v"(gf));            \
        float gg = act1, go = act1;                                          \
        asm("v_permlane32_swap_b32 %0, %1" : "+v"(gg), "+v"(go));            \
        c = fmaf(gf, c, gi * gg);                                            \
        float uc = fast_rcp(1.0f + fast_exp2(c * -2.88539008177792681472f)); \
        float tc2 = fmaf(uc, 2.0f, -1.0f);                                   \
        h = go * tc2;                                                        \
    }

    int nFull = cur / CH;   // cur is a multiple of 64, no tail

    ISSUE_CHUNK(0)
    for (int n = 0; n < nFull; ++n) {
        if (n + 1 < nFull) {
            ISSUE_CHUNK(n + 1)
            asm volatile("s_waitcnt vmcnt(8)" ::: "memory");
        } else {
            asm volatile("s_waitcnt vmcnt(0)" ::: "memory");
        }
        const float4* sb = (const float4*)(sxg + (n & 1) * (CH * FOUR_H));
        // batch the whole chunk's z into registers: 8 x ds_read_b128
        float4 z0q[4], z1q[4];
#pragma unroll
        for (int u4 = 0; u4 < 4; ++u4) {
            z0q[u4] = sb[u4 * 128 + l];
            z1q[u4] = sb[u4 * 128 + 64 + l];
        }
#pragma unroll
        for (int u4 = 0; u4 < 4; ++u4) {
            STEP_BODY(z0q[u4].x, z1q[u4].x)
            STEP_BODY(z0q[u4].y, z1q[u4].y)
            STEP_BODY(z0q[u4].z, z1q[u4].z)
            STEP_BODY(z0q[u4].w, z1q[u4].w)
        }
    }

#undef STEP_BODY
#undef ISSUE_CHUNK

    if (last) {
        float e = (h > 0.0f) ? h : (fast_exp2(h * L2E) - 1.0f);
#pragma unroll
        for (int q = 0; q < FUT; ++q) {
            float v = lowHalf ? e * Wd[kl * FUT + q] : 0.0f;
#pragma unroll
            for (int off = 1; off < 64; off <<= 1)
                v += __shfl_xor(v, off);
            if (l == 0) out[b * FUT + q] = v + bd[q];
        }
    } else {
        if (lowHalf) {
            state[b * 64 + kl]      = c;
            state[b * 64 + 32 + kl] = h;
        }
    }
}

// ---------------------------------------------------------------------------
extern "C" void kernel_launch(void* const* d_in, const int* in_sizes, int n_in,
                              void* d_out, int out_size, void* d_ws, size_t ws_size,
                              hipStream_t stream)
{
    const float* X    = (const float*)d_in[0];
    const float* Wx   = (const float*)d_in[1];
    const float* Wh   = (const float*)d_in[2];
    const float* bias = (const float*)d_in[3];
    const float* Wd   = (const float*)d_in[4];
    const float* bd   = (const float*)d_in[5];
    float* out = (float*)d_out;

    float* state = (float*)d_ws;
    size_t stateBytes = (size_t)BSZ * 64 * sizeof(float);
    float* xgbuf = (float*)((char*)d_ws + stateBytes);

    size_t avail = ws_size > stateBytes ? ws_size - stateBytes : 0;
    size_t perT = (size_t)BSZ * FOUR_H * sizeof(float);
    long TcL = (long)(avail / perT);
    TcL &= ~63L;                       // multiple of 64 (layout requirement)
    int Tc = (TcL > TT) ? TT : (int)TcL;
    if (Tc < 64) return;

    for (int t0 = 0; t0 < TT; t0 += Tc) {
        int cur = (TT - t0 < Tc) ? (TT - t0) : Tc;
        int blocks = (BSZ * cur) / 64;
        xproj_kernel<<<dim3(blocks), dim3(256), 0, stream>>>(X, Wx, bias, xgbuf, t0, cur);
        lstm_rec_kernel<<<dim3(BSZ), dim3(64), 0, stream>>>(
            xgbuf, Wh, Wd, bd, state, out, cur, (t0 == 0) ? 1 : 0,
            (t0 + cur >= TT) ? 1 : 0);
    }
}

// Round 8
// 533.543 us; speedup vs baseline: 1.7773x; 1.0057x over previous
//
#include <hip/hip_runtime.h>

#define HIDDEN 32
#define FOUR_H 128
#define FUT 6
#define BSZ 256
#define TT 2048
#define FF 64
#define CH 16                      // timesteps per LDS chunk
#define CHB (CH * FOUR_H * 4)      // 8192 bytes per chunk

typedef float f32x2 __attribute__((ext_vector_type(2)));

__device__ __forceinline__ float fast_rcp(float x)  { return __builtin_amdgcn_rcpf(x); }
__device__ __forceinline__ float fast_exp2(float x) { return __builtin_amdgcn_exp2f(x); }
__device__ __forceinline__ float sigmoid_f(float x) {
    float t = fast_exp2(x * -1.44269504088896340736f);
    return fast_rcp(1.0f + t);
}

__device__ __forceinline__ void gload_lds16(const void* g, void* l) {
    __builtin_amdgcn_global_load_lds(
        (const __attribute__((address_space(1))) void*)g,
        (__attribute__((address_space(3))) void*)l, 16, 0, 0);
}

// ---------------------------------------------------------------------------
// Kernel 1: x_proj = X @ Wx + b for timesteps [t0, t0+cur), cur % 64 == 0.
// Output layout (per batch b): chunks of 16 timesteps, each chunk stored as
// [u4][j][um] with t_in_chunk = u4*4+um  (4 sub-blocks of [128][4] floats).
// Inner loop: x tile padded to [68] so per-k x-reads are 2x ds_read_b128;
// accumulation via v_pk_fma_f32 (f32x2 column pairs).
// ---------------------------------------------------------------------------
__global__ __launch_bounds__(256) void xproj_kernel(
    const float* __restrict__ X, const float* __restrict__ Wx,
    const float* __restrict__ bias, float* __restrict__ xg,
    int t0, int cur)
{
    __shared__ float sW[64][128];
    __shared__ float sX[64][68];   // 272 B rows: 16B-aligned for every k

    int tid = threadIdx.x;
    long rowBase = (long)blockIdx.x * 64;   // 64 consecutive t within one b

    const float4* W4 = (const float4*)Wx;
    float4* sW4 = (float4*)&sW[0][0];
#pragma unroll
    for (int i = 0; i < 8; ++i) sW4[tid + 256 * i] = W4[tid + 256 * i];

#pragma unroll
    for (int i = 0; i < 4; ++i) {
        int idx = tid + 256 * i;
        int row = idx >> 4;
        int kq  = idx & 15;
        int r   = (int)rowBase + row;
        int bb  = r / cur;
        int tc  = r - bb * cur;
        const float4* xp = (const float4*)(X + ((long)bb * TT + t0 + tc) * FF);
        float4 v = xp[kq];
        sX[kq * 4 + 0][row] = v.x;
        sX[kq * 4 + 1][row] = v.y;
        sX[kq * 4 + 2][row] = v.z;
        sX[kq * 4 + 3][row] = v.w;
    }
    __syncthreads();

    int cq = tid & 31;   // column quad: cols 4*cq .. 4*cq+3
    int rg = tid >> 5;   // row group: rows 8*rg .. 8*rg+7

    float4 bv = *(const float4*)(bias + cq * 4);
    f32x2 accA[8], accB[8];
#pragma unroll
    for (int i = 0; i < 8; ++i) {
        accA[i][0] = bv.x; accA[i][1] = bv.y;
        accB[i][0] = bv.z; accB[i][1] = bv.w;
    }

#pragma unroll 4
    for (int k = 0; k < 64; ++k) {
        float4 w = *(const float4*)&sW[k][cq * 4];
        f32x2 w01 = {w.x, w.y};
        f32x2 w23 = {w.z, w.w};
        float4 xa = *(const float4*)&sX[k][rg * 8];
        float4 xb = *(const float4*)&sX[k][rg * 8 + 4];
        float xs[8] = {xa.x, xa.y, xa.z, xa.w, xb.x, xb.y, xb.z, xb.w};
#pragma unroll
        for (int i = 0; i < 8; ++i) {
            f32x2 xv = {xs[i], xs[i]};
            accA[i] = __builtin_elementwise_fma(xv, w01, accA[i]);
            accB[i] = __builtin_elementwise_fma(xv, w23, accB[i]);
        }
    }
    __syncthreads();   // done reading sW/sX; reuse sW as output staging [t][j]

#pragma unroll
    for (int i = 0; i < 8; ++i) {
        float4 o;
        o.x = accA[i][0]; o.y = accA[i][1];
        o.z = accB[i][0]; o.w = accB[i][1];
        *(float4*)&sW[rg * 8 + i][cq * 4] = o;
    }
    __syncthreads();

    // emit permuted layout with linear coalesced stores
#pragma unroll
    for (int i = 0; i < 8; ++i) {
        int f  = tid + i * 256;          // float4 index within the 32KB tile
        int j  = f & 127;
        int u4 = (f >> 7) & 3;
        int nl = f >> 9;
        int tl = nl * 16 + u4 * 4;
        float4 v;
        v.x = sW[tl + 0][j];
        v.y = sW[tl + 1][j];
        v.z = sW[tl + 2][j];
        v.w = sW[tl + 3][j];
        *(float4*)(xg + rowBase * FOUR_H + (long)f * 4) = v;
    }
}

// ---------------------------------------------------------------------------
// Kernel 2: sequential LSTM scan. One wave per batch element (1 chain/CU).
// h-broadcast via LDS: 1 ds_write_b32 + 8 uniform-address ds_read_b128
// (no readlane/SGPR traffic); GEMV = 32 v_pk_fma_f32.  (r5 proven, verbatim)
// ---------------------------------------------------------------------------
__global__ __launch_bounds__(64) void lstm_rec_kernel(
    const float* __restrict__ xg, const float* __restrict__ Wh,
    const float* __restrict__ Wd, const float* __restrict__ bd,
    float* __restrict__ state, float* __restrict__ out,
    int cur, int first, int last)
{
    __shared__ float sxg[2 * CH * FOUR_H];   // 16 KB double buffer
    __shared__ float sh[32];                 // h broadcast slab

    int b = blockIdx.x;
    int l = threadIdx.x;
    int kl = l & 31;
    bool lowHalf = (l < 32);

    // recurrent weights as k-interleaved pairs: wh0p[m] = (Wh[2m][l], Wh[2m+1][l])
    f32x2 wh0p[16], wh1p[16];
#pragma unroll
    for (int m = 0; m < 16; ++m) {
        wh0p[m][0] = Wh[(2 * m) * FOUR_H + l];
        wh0p[m][1] = Wh[(2 * m + 1) * FOUR_H + l];
        wh1p[m][0] = Wh[(2 * m) * FOUR_H + 64 + l];
        wh1p[m][1] = Wh[(2 * m + 1) * FOUR_H + 64 + l];
    }

    float c, h;
    if (first) { c = 0.0f; h = 0.0f; }
    else       { c = state[b * 64 + kl]; h = state[b * 64 + 32 + kl]; }

    const char* xpc = (const char*)(xg + (size_t)b * cur * FOUR_H);
    const float4* shq = (const float4*)sh;

    const float L2E = 1.44269504088896340736f;
    float s1 = lowHalf ? (-2.0f * L2E) : (-L2E);
    float m1 = lowHalf ? 2.0f : 1.0f;
    float a1 = lowHalf ? -1.0f : 0.0f;

#define ISSUE_CHUNK(nn)                                                      \
    {                                                                        \
        const char* src = xpc + (size_t)(nn) * CHB + l * 16;                 \
        char* dstb = (char*)sxg + ((nn) & 1) * CHB;                          \
        _Pragma("unroll")                                                    \
        for (int i = 0; i < 8; ++i)                                          \
            gload_lds16(src + i * 1024, dstb + i * 1024);                    \
    }

#define STEP_BODY(Z0, Z1)                                                    \
    {                                                                        \
        sh[kl] = h;                       /* 1 ds_write, 2-way same-addr */  \
        float4 hq[8];                                                        \
        _Pragma("unroll")                                                    \
        for (int q = 0; q < 8; ++q) hq[q] = shq[q];  /* uniform broadcast */ \
        f32x2 a0 = {(Z0), 0.0f}, b0 = {0.0f, 0.0f};                          \
        f32x2 a1v = {(Z1), 0.0f}, b1 = {0.0f, 0.0f};                         \
        _Pragma("unroll")                                                    \
        for (int q = 0; q < 8; ++q) {                                        \
            f32x2 hlo = {hq[q].x, hq[q].y};                                  \
            f32x2 hhi = {hq[q].z, hq[q].w};                                  \
            a0  = __builtin_elementwise_fma(hlo, wh0p[2 * q],     a0);       \
            b0  = __builtin_elementwise_fma(hhi, wh0p[2 * q + 1], b0);       \
            a1v = __builtin_elementwise_fma(hlo, wh1p[2 * q],     a1v);      \
            b1  = __builtin_elementwise_fma(hhi, wh1p[2 * q + 1], b1);       \
        }                                                                    \
        f32x2 s0p = a0 + b0;                                                 \
        f32x2 s1p = a1v + b1;                                                \
        float A0 = s0p[0] + s0p[1];                                          \
        float A1 = s1p[0] + s1p[1];                                          \
        float act0 = sigmoid_f(A0);                                          \
        float u1 = fast_rcp(1.0f + fast_exp2(A1 * s1));                      \
        float act1 = fmaf(u1, m1, a1);                                       \
        float gi = act0, gf = act0;                                          \
        asm("v_permlane32_swap_b32 %0, %1" : "+v"(gi), "+v"(gf));            \
        float gg = act1, go = act1;                                          \
        asm("v_permlane32_swap_b32 %0, %1" : "+v"(gg), "+v"(go));            \
        c = fmaf(gf, c, gi * gg);                                            \
        float uc = fast_rcp(1.0f + fast_exp2(c * -2.88539008177792681472f)); \
        float tc2 = fmaf(uc, 2.0f, -1.0f);                                   \
        h = go * tc2;                                                        \
    }

    int nFull = cur / CH;   // cur is a multiple of 64, no tail

    ISSUE_CHUNK(0)
    for (int n = 0; n < nFull; ++n) {
        if (n + 1 < nFull) {
            ISSUE_CHUNK(n + 1)
            asm volatile("s_waitcnt vmcnt(8)" ::: "memory");
        } else {
            asm volatile("s_waitcnt vmcnt(0)" ::: "memory");
        }
        const float4* sb = (const float4*)(sxg + (n & 1) * (CH * FOUR_H));
        // batch the whole chunk's z into registers: 8 x ds_read_b128
        float4 z0q[4], z1q[4];
#pragma unroll
        for (int u4 = 0; u4 < 4; ++u4) {
            z0q[u4] = sb[u4 * 128 + l];
            z1q[u4] = sb[u4 * 128 + 64 + l];
        }
#pragma unroll
        for (int u4 = 0; u4 < 4; ++u4) {
            STEP_BODY(z0q[u4].x, z1q[u4].x)
            STEP_BODY(z0q[u4].y, z1q[u4].y)
            STEP_BODY(z0q[u4].z, z1q[u4].z)
            STEP_BODY(z0q[u4].w, z1q[u4].w)
        }
    }

#undef STEP_BODY
#undef ISSUE_CHUNK

    if (last) {
        float e = (h > 0.0f) ? h : (fast_exp2(h * L2E) - 1.0f);
#pragma unroll
        for (int q = 0; q < FUT; ++q) {
            float v = lowHalf ? e * Wd[kl * FUT + q] : 0.0f;
#pragma unroll
            for (int off = 1; off < 64; off <<= 1)
                v += __shfl_xor(v, off);
            if (l == 0) out[b * FUT + q] = v + bd[q];
        }
    } else {
        if (lowHalf) {
            state[b * 64 + kl]      = c;
            state[b * 64 + 32 + kl] = h;
        }
    }
}

// ---------------------------------------------------------------------------
extern "C" void kernel_launch(void* const* d_in, const int* in_sizes, int n_in,
                              void* d_out, int out_size, void* d_ws, size_t ws_size,
                              hipStream_t stream)
{
    const float* X    = (const float*)d_in[0];
    const float* Wx   = (const float*)d_in[1];
    const float* Wh   = (const float*)d_in[2];
    const float* bias = (const float*)d_in[3];
    const float* Wd   = (const float*)d_in[4];
    const float* bd   = (const float*)d_in[5];
    float* out = (float*)d_out;

    float* state = (float*)d_ws;
    size_t stateBytes = (size_t)BSZ * 64 * sizeof(float);
    float* xgbuf = (float*)((char*)d_ws + stateBytes);

    size_t avail = ws_size > stateBytes ? ws_size - stateBytes : 0;
    size_t perT = (size_t)BSZ * FOUR_H * sizeof(float);
    long TcL = (long)(avail / perT);
    TcL &= ~63L;                       // multiple of 64 (layout requirement)
    int Tc = (TcL > TT) ? TT : (int)TcL;
    if (Tc < 64) return;

    for (int t0 = 0; t0 < TT; t0 += Tc) {
        int cur = (TT - t0 < Tc) ? (TT - t0) : Tc;
        int blocks = (BSZ * cur) / 64;
        xproj_kernel<<<dim3(blocks), dim3(256), 0, stream>>>(X, Wx, bias, xgbuf, t0, cur);
        lstm_rec_kernel<<<dim3(BSZ), dim3(64), 0, stream>>>(
            xgbuf, Wh, Wd, bd, state, out, cur, (t0 == 0) ? 1 : 0,
            (t0 + cur >= TT) ? 1 : 0);
    }
}

// Round 9
// 521.140 us; speedup vs baseline: 1.8196x; 1.0238x over previous
//
#include <hip/hip_runtime.h>

#define FOUR_H 128
#define FUT 6
#define BSZ 256
#define TT 2048
#define FF 64
#define CH 16
#define NCH (TT / CH)              // 128 chunks of 16 timesteps

typedef float f32x2 __attribute__((ext_vector_type(2)));
typedef float f32x4 __attribute__((ext_vector_type(4)));
typedef unsigned int u32;
typedef u32 u32x4 __attribute__((ext_vector_type(4)));
typedef short bf16x8 __attribute__((ext_vector_type(8)));

__device__ __forceinline__ float fast_rcp(float x)  { return __builtin_amdgcn_rcpf(x); }
__device__ __forceinline__ float fast_exp2(float x) { return __builtin_amdgcn_exp2f(x); }
__device__ __forceinline__ float sigmoid_f(float x) {
    float t = fast_exp2(x * -1.44269504088896340736f);
    return fast_rcp(1.0f + t);
}
__device__ __forceinline__ u32 f2u(float x) { return __builtin_bit_cast(u32, x); }
__device__ __forceinline__ float u2f(u32 x) { return __builtin_bit_cast(float, x); }

__device__ __forceinline__ void gload_lds16(const void* g, void* l) {
    __builtin_amdgcn_global_load_lds(
        (const __attribute__((address_space(1))) void*)g,
        (__attribute__((address_space(3))) void*)l, 16, 0, 0);
}

__device__ __forceinline__ f32x4 mfma16(bf16x8 a, bf16x8 b, f32x4 c) {
    return __builtin_amdgcn_mfma_f32_16x16x32_bf16(a, b, c, 0, 0, 0);
}

// ===========================================================================
// One kernel does everything. 256 blocks x 1 wave; block b owns batch b.
// Per 16-step chunk: Z = X_chunk @ Wx + bias via split-bf16 MFMA
// (hi/lo truncation split, 3 MFMAs per tile, rel err ~2^-16), written to a
// double-buffered LDS zbuf in [u4][j][um] layout; then 16 serial LSTM steps
// (proven r5 step body: LDS h-broadcast + v_pk_fma_f32 GEMV + permlane swaps).
// X is streamed HBM->LDS with global_load_lds using XOR-preswizzled source
// addresses so A-fragment ds_read_b128s are bank-conflict-free.
// ===========================================================================
__global__ __launch_bounds__(64) void lstm_fused(
    const float* __restrict__ X, const float* __restrict__ Wx,
    const float* __restrict__ bias, const float* __restrict__ Wh,
    const float* __restrict__ Wd, const float* __restrict__ bd,
    float* __restrict__ out)
{
    __shared__ float xstage[2 * CH * FF];     // 8 KB  X double buffer
    __shared__ float zbuf[2 * CH * FOUR_H];   // 16 KB Z double buffer
    __shared__ u32x4 wfrag[8 * 2 * 2 * 64];   // 32 KB Wx frags [n][ks][hi/lo][lane]
    __shared__ float sh[32];                  // h broadcast slab

    int b  = blockIdx.x;
    int l  = threadIdx.x;
    int kl = l & 31;
    int lr = l >> 4;       // lane k-group 0..3
    int lc = l & 15;       // lane row/col within tile
    bool lowHalf = (l < 32);

    // ---- recurrent weights as k-interleaved f32 pairs (r5, proven) ----
    f32x2 wh0p[16], wh1p[16];
#pragma unroll
    for (int m = 0; m < 16; ++m) {
        wh0p[m][0] = Wh[(2 * m) * FOUR_H + l];
        wh0p[m][1] = Wh[(2 * m + 1) * FOUR_H + l];
        wh1p[m][0] = Wh[(2 * m) * FOUR_H + 64 + l];
        wh1p[m][1] = Wh[(2 * m + 1) * FOUR_H + 64 + l];
    }

    // ---- bias per n-tile (accumulator init; C col = lane&15) ----
    float bj[8];
#pragma unroll
    for (int n = 0; n < 8; ++n) bj[n] = bias[n * 16 + lc];

    // ---- one-time: split Wx into bf16 hi/lo B-fragments in LDS ----
    // B-frag for tile n, kstep ks: lane l holds B[k][j], j = n*16+lc,
    // k = ks*32 + lr*8 + e (e=0..7), packed 2 bf16 per u32 (even elem low).
    const u32 PSEL = 0x07060302u;   // perm: {b0.hi16, b1.hi16} -> one u32
#pragma unroll 2
    for (int n = 0; n < 8; ++n)
        for (int ks = 0; ks < 2; ++ks) {
            u32 hi[4], lo[4];
#pragma unroll
            for (int e = 0; e < 4; ++e) {
                int k0 = ks * 32 + lr * 8 + 2 * e;
                float w0 = Wx[k0 * FOUR_H + n * 16 + lc];
                float w1 = Wx[(k0 + 1) * FOUR_H + n * 16 + lc];
                u32 x0 = f2u(w0), x1 = f2u(w1);
                hi[e] = __builtin_amdgcn_perm(x1, x0, PSEL);
                float l0 = w0 - u2f(x0 & 0xFFFF0000u);
                float l1 = w1 - u2f(x1 & 0xFFFF0000u);
                lo[e] = __builtin_amdgcn_perm(f2u(l1), f2u(l0), PSEL);
            }
            wfrag[((n * 2 + ks) * 2 + 0) * 64 + l] = (u32x4){hi[0], hi[1], hi[2], hi[3]};
            wfrag[((n * 2 + ks) * 2 + 1) * 64 + l] = (u32x4){lo[0], lo[1], lo[2], lo[3]};
        }

    float c = 0.0f, h = 0.0f;
    const char* Xb = (const char*)(X + (size_t)b * TT * FF);
    const float4* shq = (const float4*)sh;

    const float L2E = 1.44269504088896340736f;
    float s1 = lowHalf ? (-2.0f * L2E) : (-L2E);
    float m1 = lowHalf ? 2.0f : 1.0f;
    float a1 = lowHalf ? -1.0f : 0.0f;

    // per-lane XOR-preswizzled gload source offsets (4KB chunk, 16B units):
    // LDS slot (t, q') holds global chunk q = q' ^ t  -> A-reads conflict-free
    int soff[4];
#pragma unroll
    for (int i = 0; i < 4; ++i) {
        int t = i * 4 + lr;
        soff[i] = t * 256 + ((lc ^ t) << 4);
    }

#define GLOAD(mm)                                                            \
    {                                                                        \
        const char* src = Xb + (size_t)(mm) * 4096;                          \
        char* dst = (char*)xstage + ((mm) & 1) * 4096;                       \
        _Pragma("unroll")                                                    \
        for (int i = 0; i < 4; ++i)                                          \
            gload_lds16(src + soff[i], dst + i * 1024);                      \
    }

    // Z for chunk mm: A-frag row=lc, k = ks*32 + lr*8 + e (swizzled read);
    // 3 MFMAs per (n,ks): hi*hi + hi*lo + lo*hi. D row=(lr*4+r), col=lc.
#define ZPREP(mm)                                                            \
    {                                                                        \
        f32x4 zacc[8];                                                       \
        _Pragma("unroll")                                                    \
        for (int n = 0; n < 8; ++n)                                          \
            zacc[n] = (f32x4){bj[n], bj[n], bj[n], bj[n]};                   \
        const char* xs = (const char*)xstage + ((mm) & 1) * 4096;            \
        _Pragma("unroll")                                                    \
        for (int ks = 0; ks < 2; ++ks) {                                     \
            int q0 = ks * 8 + lr * 2;                                        \
            int aoff = lc * 256 + ((q0 ^ lc) << 4);                          \
            u32x4 xa = *(const u32x4*)(xs + aoff);                           \
            u32x4 xv = *(const u32x4*)(xs + (aoff ^ 16));                    \
            u32 h0 = __builtin_amdgcn_perm(xa.y, xa.x, PSEL);                \
            u32 h1 = __builtin_amdgcn_perm(xa.w, xa.z, PSEL);                \
            u32 h2 = __builtin_amdgcn_perm(xv.y, xv.x, PSEL);                \
            u32 h3 = __builtin_amdgcn_perm(xv.w, xv.z, PSEL);                \
            float d0 = u2f(xa.x) - u2f(xa.x & 0xFFFF0000u);                  \
            float d1 = u2f(xa.y) - u2f(xa.y & 0xFFFF0000u);                  \
            float d2 = u2f(xa.z) - u2f(xa.z & 0xFFFF0000u);                  \
            float d3 = u2f(xa.w) - u2f(xa.w & 0xFFFF0000u);                  \
            float d4 = u2f(xv.x) - u2f(xv.x & 0xFFFF0000u);                  \
            float d5 = u2f(xv.y) - u2f(xv.y & 0xFFFF0000u);                  \
            float d6 = u2f(xv.z) - u2f(xv.z & 0xFFFF0000u);                  \
            float d7 = u2f(xv.w) - u2f(xv.w & 0xFFFF0000u);                  \
            u32 g0 = __builtin_amdgcn_perm(f2u(d1), f2u(d0), PSEL);          \
            u32 g1 = __builtin_amdgcn_perm(f2u(d3), f2u(d2), PSEL);          \
            u32 g2 = __builtin_amdgcn_perm(f2u(d5), f2u(d4), PSEL);          \
            u32 g3 = __builtin_amdgcn_perm(f2u(d7), f2u(d6), PSEL);          \
            bf16x8 ahi = __builtin_bit_cast(bf16x8, (u32x4){h0, h1, h2, h3});\
            bf16x8 alo = __builtin_bit_cast(bf16x8, (u32x4){g0, g1, g2, g3});\
            _Pragma("unroll")                                                \
            for (int n = 0; n < 8; ++n) {                                    \
                bf16x8 bh = __builtin_bit_cast(bf16x8,                       \
                    wfrag[((n * 2 + ks) * 2 + 0) * 64 + l]);                 \
                bf16x8 bl = __builtin_bit_cast(bf16x8,                       \
                    wfrag[((n * 2 + ks) * 2 + 1) * 64 + l]);                 \
                zacc[n] = mfma16(ahi, bh, zacc[n]);                          \
                zacc[n] = mfma16(ahi, bl, zacc[n]);                          \
                zacc[n] = mfma16(alo, bh, zacc[n]);                          \
            }                                                                \
        }                                                                    \
        f32x4* zo = (f32x4*)zbuf + ((mm) & 1) * 512 + lr * 128 + lc;         \
        _Pragma("unroll")                                                    \
        for (int n = 0; n < 8; ++n) zo[n * 16] = zacc[n];                    \
    }

#define STEP_BODY(Z0, Z1)                                                    \
    {                                                                        \
        sh[kl] = h;                                                          \
        float4 hq[8];                                                        \
        _Pragma("unroll")                                                    \
        for (int q = 0; q < 8; ++q) hq[q] = shq[q];                          \
        f32x2 a0 = {(Z0), 0.0f}, b0 = {0.0f, 0.0f};                          \
        f32x2 a1v = {(Z1), 0.0f}, b1 = {0.0f, 0.0f};                         \
        _Pragma("unroll")                                                    \
        for (int q = 0; q < 8; ++q) {                                        \
            f32x2 hlo = {hq[q].x, hq[q].y};                                  \
            f32x2 hhi = {hq[q].z, hq[q].w};                                  \
            a0  = __builtin_elementwise_fma(hlo, wh0p[2 * q],     a0);       \
            b0  = __builtin_elementwise_fma(hhi, wh0p[2 * q + 1], b0);       \
            a1v = __builtin_elementwise_fma(hlo, wh1p[2 * q],     a1v);      \
            b1  = __builtin_elementwise_fma(hhi, wh1p[2 * q + 1], b1);       \
        }                                                                    \
        f32x2 s0p = a0 + b0;                                                 \
        f32x2 s1p = a1v + b1;                                                \
        float A0 = s0p[0] + s0p[1];                                          \
        float A1 = s1p[0] + s1p[1];                                          \
        float act0 = sigmoid_f(A0);                                          \
        float u1 = fast_rcp(1.0f + fast_exp2(A1 * s1));                      \
        float act1 = fmaf(u1, m1, a1);                                       \
        float gi = act0, gf = act0;                                          \
        asm("v_permlane32_swap_b32 %0, %1" : "+v"(gi), "+v"(gf));            \
        float gg = act1, go = act1;                                          \
        asm("v_permlane32_swap_b32 %0, %1" : "+v"(gg), "+v"(go));            \
        c = fmaf(gf, c, gi * gg);                                            \
        float uc = fast_rcp(1.0f + fast_exp2(c * -2.88539008177792681472f)); \
        float tc2 = fmaf(uc, 2.0f, -1.0f);                                   \
        h = go * tc2;                                                        \
    }

    // ---- pipeline prologue ----
    GLOAD(0)
    GLOAD(1)
    asm volatile("s_waitcnt vmcnt(4)" ::: "memory");   // X_0 landed
    ZPREP(0)

    for (int m = 0; m < NCH; ++m) {
        // this chunk's z into registers (8 x ds_read_b128, 2-way = free)
        const float4* zb = (const float4*)zbuf + (m & 1) * 512;
        float4 z0q[4], z1q[4];
#pragma unroll
        for (int u4 = 0; u4 < 4; ++u4) {
            z0q[u4] = zb[u4 * 128 + l];
            z1q[u4] = zb[u4 * 128 + 64 + l];
        }

        if (m + 2 < NCH) { GLOAD(m + 2) }
        if (m + 1 < NCH) {
            if (m + 2 < NCH)
                asm volatile("s_waitcnt vmcnt(4)" ::: "memory"); // X_{m+1} landed
            else
                asm volatile("s_waitcnt vmcnt(0)" ::: "memory");
            ZPREP(m + 1)
        }

#pragma unroll
        for (int u4 = 0; u4 < 4; ++u4) {
            STEP_BODY(z0q[u4].x, z1q[u4].x)
            STEP_BODY(z0q[u4].y, z1q[u4].y)
            STEP_BODY(z0q[u4].z, z1q[u4].z)
            STEP_BODY(z0q[u4].w, z1q[u4].w)
        }
    }

#undef STEP_BODY
#undef ZPREP
#undef GLOAD

    // ---- head: out = elu(h_T) @ Wd + bd ----
    {
        float e = (h > 0.0f) ? h : (fast_exp2(h * L2E) - 1.0f);
#pragma unroll
        for (int q = 0; q < FUT; ++q) {
            float v = lowHalf ? e * Wd[kl * FUT + q] : 0.0f;
#pragma unroll
            for (int off = 1; off < 64; off <<= 1)
                v += __shfl_xor(v, off);
            if (l == 0) out[b * FUT + q] = v + bd[q];
        }
    }
}

// ---------------------------------------------------------------------------
extern "C" void kernel_launch(void* const* d_in, const int* in_sizes, int n_in,
                              void* d_out, int out_size, void* d_ws, size_t ws_size,
                              hipStream_t stream)
{
    const float* X    = (const float*)d_in[0];
    const float* Wx   = (const float*)d_in[1];
    const float* Wh   = (const float*)d_in[2];
    const float* bias = (const float*)d_in[3];
    const float* Wd   = (const float*)d_in[4];
    const float* bd   = (const float*)d_in[5];
    float* out = (float*)d_out;

    lstm_fused<<<dim3(BSZ), dim3(64), 0, stream>>>(X, Wx, bias, Wh, Wd, bd, out);
}

// Round 10
// 348.146 us; speedup vs baseline: 2.7237x; 1.4969x over previous
//
#include <hip/hip_runtime.h>

#define FOUR_H 128
#define FUT 6
#define BSZ 256
#define TT 2048
#define FF 64
#define CH 16
#define NCH (TT / CH)              // 128 chunks of 16 timesteps

typedef float f32x2 __attribute__((ext_vector_type(2)));
typedef float f32x4 __attribute__((ext_vector_type(4)));
typedef unsigned int u32;
typedef u32 u32x4 __attribute__((ext_vector_type(4)));
typedef short bf16x8 __attribute__((ext_vector_type(8)));

__device__ __forceinline__ float fast_rcp(float x)  { return __builtin_amdgcn_rcpf(x); }
__device__ __forceinline__ float fast_exp2(float x) { return __builtin_amdgcn_exp2f(x); }
__device__ __forceinline__ float sigmoid_f(float x) {
    float t = fast_exp2(x * -1.44269504088896340736f);
    return fast_rcp(1.0f + t);
}
__device__ __forceinline__ u32 f2u(float x) { return __builtin_bit_cast(u32, x); }
__device__ __forceinline__ float u2f(u32 x) { return __builtin_bit_cast(float, x); }

__device__ __forceinline__ void gload_lds16(const void* g, void* l) {
    __builtin_amdgcn_global_load_lds(
        (const __attribute__((address_space(1))) void*)g,
        (__attribute__((address_space(3))) void*)l, 16, 0, 0);
}

__device__ __forceinline__ f32x4 mfma16(bf16x8 a, bf16x8 b, f32x4 c) {
    return __builtin_amdgcn_mfma_f32_16x16x32_bf16(a, b, c, 0, 0, 0);
}

// ===========================================================================
// 256 blocks x 2 waves. Block b owns batch b.
//   wave 0 (SIMD i): the serial LSTM scan — r5-proven step body, NOTHING else.
//   wave 1 (SIMD j != i): X prefetch (global_load_lds, 2-deep) + split-bf16
//     MFMA x-projection into double-buffered zbuf. One __syncthreads per
//     16-step chunk hands zbuf halves over; wave 1 is ~9x faster per chunk
//     so it parks at the barrier.
// ===========================================================================
__global__ __launch_bounds__(128) void lstm_fused(
    const float* __restrict__ X, const float* __restrict__ Wx,
    const float* __restrict__ bias, const float* __restrict__ Wh,
    const float* __restrict__ Wd, const float* __restrict__ bd,
    float* __restrict__ out)
{
    __shared__ float xstage[2 * CH * FF];     // 8 KB  X double buffer (wave 1)
    __shared__ float zbuf[2 * CH * FOUR_H];   // 16 KB Z double buffer (1 -> 0)
    __shared__ u32x4 wfrag[8 * 2 * 2 * 64];   // 32 KB Wx bf16 hi/lo frags (wave 1)
    __shared__ float sh[32];                  // h broadcast slab (wave 0)

    int wv = threadIdx.x >> 6;
    int b  = blockIdx.x;
    int l  = threadIdx.x & 63;
    int kl = l & 31;
    int lr = l >> 4;       // lane k-group 0..3
    int lc = l & 15;       // lane row/col within tile
    bool lowHalf = (l < 32);

    const u32 PSEL = 0x07060302u;   // perm: {b0.hi16, b1.hi16} -> one u32
    const char* Xb = (const char*)(X + (size_t)b * TT * FF);

    // ---------------- wave-0 state (consumer) ----------------
    f32x2 wh0p[16], wh1p[16];
    float c = 0.0f, h = 0.0f;
    const float4* shq = (const float4*)sh;
    const float L2E = 1.44269504088896340736f;
    float s1 = lowHalf ? (-2.0f * L2E) : (-L2E);
    float m1 = lowHalf ? 2.0f : 1.0f;
    float a1 = lowHalf ? -1.0f : 0.0f;

    // ---------------- wave-1 state (producer) ----------------
    float bj[8];
    int soff[4];

    if (wv == 0) {
#pragma unroll
        for (int m = 0; m < 16; ++m) {
            wh0p[m][0] = Wh[(2 * m) * FOUR_H + l];
            wh0p[m][1] = Wh[(2 * m + 1) * FOUR_H + l];
            wh1p[m][0] = Wh[(2 * m) * FOUR_H + 64 + l];
            wh1p[m][1] = Wh[(2 * m + 1) * FOUR_H + 64 + l];
        }
    } else {
#pragma unroll
        for (int n = 0; n < 8; ++n) bj[n] = bias[n * 16 + lc];
        // XOR-preswizzled gload source offsets (4KB chunk, 16B units):
        // LDS slot (t, q') holds global chunk q = q' ^ t
#pragma unroll
        for (int i = 0; i < 4; ++i) {
            int t = i * 4 + lr;
            soff[i] = t * 256 + ((lc ^ t) << 4);
        }
        // one-time: split Wx into bf16 hi/lo B-fragments in LDS.
        // B-frag tile n, kstep ks: lane l holds B[k][j], j=n*16+lc,
        // k = ks*32 + lr*8 + e, packed 2 bf16/u32 (even elem low).
#pragma unroll 2
        for (int n = 0; n < 8; ++n)
            for (int ks = 0; ks < 2; ++ks) {
                u32 hi[4], lo[4];
#pragma unroll
                for (int e = 0; e < 4; ++e) {
                    int k0 = ks * 32 + lr * 8 + 2 * e;
                    float w0 = Wx[k0 * FOUR_H + n * 16 + lc];
                    float w1 = Wx[(k0 + 1) * FOUR_H + n * 16 + lc];
                    u32 x0 = f2u(w0), x1 = f2u(w1);
                    hi[e] = __builtin_amdgcn_perm(x1, x0, PSEL);
                    float l0 = w0 - u2f(x0 & 0xFFFF0000u);
                    float l1 = w1 - u2f(x1 & 0xFFFF0000u);
                    lo[e] = __builtin_amdgcn_perm(f2u(l1), f2u(l0), PSEL);
                }
                wfrag[((n * 2 + ks) * 2 + 0) * 64 + l] = (u32x4){hi[0], hi[1], hi[2], hi[3]};
                wfrag[((n * 2 + ks) * 2 + 1) * 64 + l] = (u32x4){lo[0], lo[1], lo[2], lo[3]};
            }
    }

#define GLOAD(mm)                                                            \
    {                                                                        \
        const char* src = Xb + (size_t)(mm) * 4096;                          \
        char* dst = (char*)xstage + ((mm) & 1) * 4096;                       \
        _Pragma("unroll")                                                    \
        for (int i = 0; i < 4; ++i)                                          \
            gload_lds16(src + soff[i], dst + i * 1024);                      \
    }

    // Z for chunk mm: A-frag row=lc, k = ks*32+lr*8+e (swizzled read);
    // 3 MFMAs per (n,ks): hi*hi + hi*lo + lo*hi. D row=(lr*4+r), col=lc.
#define ZPREP(mm)                                                            \
    {                                                                        \
        f32x4 zacc[8];                                                       \
        _Pragma("unroll")                                                    \
        for (int n = 0; n < 8; ++n)                                          \
            zacc[n] = (f32x4){bj[n], bj[n], bj[n], bj[n]};                   \
        const char* xs = (const char*)xstage + ((mm) & 1) * 4096;            \
        _Pragma("unroll")                                                    \
        for (int ks = 0; ks < 2; ++ks) {                                     \
            int q0 = ks * 8 + lr * 2;                                        \
            int aoff = lc * 256 + ((q0 ^ lc) << 4);                          \
            u32x4 xa = *(const u32x4*)(xs + aoff);                           \
            u32x4 xv = *(const u32x4*)(xs + (aoff ^ 16));                    \
            u32 h0 = __builtin_amdgcn_perm(xa.y, xa.x, PSEL);                \
            u32 h1 = __builtin_amdgcn_perm(xa.w, xa.z, PSEL);                \
            u32 h2 = __builtin_amdgcn_perm(xv.y, xv.x, PSEL);                \
            u32 h3 = __builtin_amdgcn_perm(xv.w, xv.z, PSEL);                \
            float d0 = u2f(xa.x) - u2f(xa.x & 0xFFFF0000u);                  \
            float d1 = u2f(xa.y) - u2f(xa.y & 0xFFFF0000u);                  \
            float d2 = u2f(xa.z) - u2f(xa.z & 0xFFFF0000u);                  \
            float d3 = u2f(xa.w) - u2f(xa.w & 0xFFFF0000u);                  \
            float d4 = u2f(xv.x) - u2f(xv.x & 0xFFFF0000u);                  \
            float d5 = u2f(xv.y) - u2f(xv.y & 0xFFFF0000u);                  \
            float d6 = u2f(xv.z) - u2f(xv.z & 0xFFFF0000u);                  \
            float d7 = u2f(xv.w) - u2f(xv.w & 0xFFFF0000u);                  \
            u32 g0 = __builtin_amdgcn_perm(f2u(d1), f2u(d0), PSEL);          \
            u32 g1 = __builtin_amdgcn_perm(f2u(d3), f2u(d2), PSEL);          \
            u32 g2 = __builtin_amdgcn_perm(f2u(d5), f2u(d4), PSEL);          \
            u32 g3 = __builtin_amdgcn_perm(f2u(d7), f2u(d6), PSEL);          \
            bf16x8 ahi = __builtin_bit_cast(bf16x8, (u32x4){h0, h1, h2, h3});\
            bf16x8 alo = __builtin_bit_cast(bf16x8, (u32x4){g0, g1, g2, g3});\
            _Pragma("unroll")                                                \
            for (int n = 0; n < 8; ++n) {                                    \
                bf16x8 bh = __builtin_bit_cast(bf16x8,                       \
                    wfrag[((n * 2 + ks) * 2 + 0) * 64 + l]);                 \
                bf16x8 bl = __builtin_bit_cast(bf16x8,                       \
                    wfrag[((n * 2 + ks) * 2 + 1) * 64 + l]);                 \
                zacc[n] = mfma16(ahi, bh, zacc[n]);                          \
                zacc[n] = mfma16(ahi, bl, zacc[n]);                          \
                zacc[n] = mfma16(alo, bh, zacc[n]);                          \
            }                                                                \
        }                                                                    \
        f32x4* zo = (f32x4*)zbuf + ((mm) & 1) * 512 + lr * 128 + lc;         \
        _Pragma("unroll")                                                    \
        for (int n = 0; n < 8; ++n) zo[n * 16] = zacc[n];                    \
    }

#define STEP_BODY(Z0, Z1)                                                    \
    {                                                                        \
        sh[kl] = h;                                                          \
        float4 hq[8];                                                        \
        _Pragma("unroll")                                                    \
        for (int q = 0; q < 8; ++q) hq[q] = shq[q];                          \
        f32x2 a0 = {(Z0), 0.0f}, b0 = {0.0f, 0.0f};                          \
        f32x2 a1v = {(Z1), 0.0f}, b1 = {0.0f, 0.0f};                         \
        _Pragma("unroll")                                                    \
        for (int q = 0; q < 8; ++q) {                                        \
            f32x2 hlo = {hq[q].x, hq[q].y};                                  \
            f32x2 hhi = {hq[q].z, hq[q].w};                                  \
            a0  = __builtin_elementwise_fma(hlo, wh0p[2 * q],     a0);       \
            b0  = __builtin_elementwise_fma(hhi, wh0p[2 * q + 1], b0);       \
            a1v = __builtin_elementwise_fma(hlo, wh1p[2 * q],     a1v);      \
            b1  = __builtin_elementwise_fma(hhi, wh1p[2 * q + 1], b1);       \
        }                                                                    \
        f32x2 s0p = a0 + b0;                                                 \
        f32x2 s1p = a1v + b1;                                                \
        float A0 = s0p[0] + s0p[1];                                          \
        float A1 = s1p[0] + s1p[1];                                          \
        float act0 = sigmoid_f(A0);                                          \
        float u1 = fast_rcp(1.0f + fast_exp2(A1 * s1));                      \
        float act1 = fmaf(u1, m1, a1);                                       \
        float gi = act0, gf = act0;                                          \
        asm("v_permlane32_swap_b32 %0, %1" : "+v"(gi), "+v"(gf));            \
        float gg = act1, go = act1;                                          \
        asm("v_permlane32_swap_b32 %0, %1" : "+v"(gg), "+v"(go));            \
        c = fmaf(gf, c, gi * gg);                                            \
        float uc = fast_rcp(1.0f + fast_exp2(c * -2.88539008177792681472f)); \
        float tc2 = fmaf(uc, 2.0f, -1.0f);                                   \
        h = go * tc2;                                                        \
    }

    // ---- prologue: wave 1 fills zbuf[0] ----
    if (wv == 1) {
        GLOAD(0)
        GLOAD(1)
        asm volatile("s_waitcnt vmcnt(4)" ::: "memory");   // X_0 landed
        ZPREP(0)
    }
    __syncthreads();

    for (int m = 0; m < NCH; ++m) {
        if (wv == 1) {
            // produce chunk m+1 into zbuf[(m+1)&1] while wave 0 eats zbuf[m&1]
            if (m + 1 < NCH) {
                if (m + 2 < NCH) {
                    GLOAD(m + 2)
                    asm volatile("s_waitcnt vmcnt(4)" ::: "memory");  // X_{m+1} landed
                } else {
                    asm volatile("s_waitcnt vmcnt(0)" ::: "memory");
                }
                ZPREP(m + 1)
            }
        } else {
            const float4* zb = (const float4*)zbuf + (m & 1) * 512;
            float4 z0q[4], z1q[4];
#pragma unroll
            for (int u4 = 0; u4 < 4; ++u4) {
                z0q[u4] = zb[u4 * 128 + l];
                z1q[u4] = zb[u4 * 128 + 64 + l];
            }
#pragma unroll
            for (int u4 = 0; u4 < 4; ++u4) {
                STEP_BODY(z0q[u4].x, z1q[u4].x)
                STEP_BODY(z0q[u4].y, z1q[u4].y)
                STEP_BODY(z0q[u4].z, z1q[u4].z)
                STEP_BODY(z0q[u4].w, z1q[u4].w)
            }
        }
        __syncthreads();
    }

#undef STEP_BODY
#undef ZPREP
#undef GLOAD

    // ---- head: out = elu(h_T) @ Wd + bd (wave 0 only) ----
    if (wv == 0) {
        float e = (h > 0.0f) ? h : (fast_exp2(h * L2E) - 1.0f);
#pragma unroll
        for (int q = 0; q < FUT; ++q) {
            float v = lowHalf ? e * Wd[kl * FUT + q] : 0.0f;
#pragma unroll
            for (int off = 1; off < 64; off <<= 1)
                v += __shfl_xor(v, off);
            if (l == 0) out[b * FUT + q] = v + bd[q];
        }
    }
}

// ---------------------------------------------------------------------------
extern "C" void kernel_launch(void* const* d_in, const int* in_sizes, int n_in,
                              void* d_out, int out_size, void* d_ws, size_t ws_size,
                              hipStream_t stream)
{
    const float* X    = (const float*)d_in[0];
    const float* Wx   = (const float*)d_in[1];
    const float* Wh   = (const float*)d_in[2];
    const float* bias = (const float*)d_in[3];
    const float* Wd   = (const float*)d_in[4];
    const float* bd   = (const float*)d_in[5];
    float* out = (float*)d_out;

    lstm_fused<<<dim3(BSZ), dim3(128), 0, stream>>>(X, Wx, bias, Wh, Wd, bd, out);
}